// Round 10
// baseline (2003.504 us; speedup 1.0000x reference)
//
#include <hip/hip_runtime.h>
#include <hip/hip_bf16.h>
#include <hip/hip_cooperative_groups.h>
#include <cstdint>
#include <cstddef>

namespace cg = cooperative_groups;

#define NGRAPHS 64

typedef short bf16x8 __attribute__((ext_vector_type(8)));
typedef float f32x4 __attribute__((ext_vector_type(4)));

__device__ inline float bf2f(unsigned short u) {
    return __uint_as_float(((unsigned)u) << 16);
}
__device__ inline unsigned short f2bf(float f) {
    unsigned u = __float_as_uint(f);
    return (unsigned short)((u + 0x7fff + ((u >> 16) & 1)) >> 16);  // RNE
}
__device__ inline void unpack8(uint4 u, float* v) {
    v[0] = bf2f((unsigned short)(u.x & 0xffff)); v[1] = bf2f((unsigned short)(u.x >> 16));
    v[2] = bf2f((unsigned short)(u.y & 0xffff)); v[3] = bf2f((unsigned short)(u.y >> 16));
    v[4] = bf2f((unsigned short)(u.z & 0xffff)); v[5] = bf2f((unsigned short)(u.z >> 16));
    v[6] = bf2f((unsigned short)(u.w & 0xffff)); v[7] = bf2f((unsigned short)(u.w >> 16));
}

// ================= device phase bodies (shared between coop and fallback) =================

__device__ void scan1_body(const int* __restrict__ cnt, int* __restrict__ offs,
                           int* __restrict__ bsum, float* __restrict__ dinv, int n) {
    __shared__ int lds1[256];
    int t = threadIdx.x;
    int base = blockIdx.x * 1024 + t * 4;
    int4 v = {0, 0, 0, 0};
    if (base + 3 < n) v = *reinterpret_cast<const int4*>(cnt + base);
    else {
        if (base + 0 < n) v.x = cnt[base + 0];
        if (base + 1 < n) v.y = cnt[base + 1];
        if (base + 2 < n) v.z = cnt[base + 2];
    }
    if (base + 0 < n) dinv[base + 0] = rsqrtf((float)(v.x + 1));
    if (base + 1 < n) dinv[base + 1] = rsqrtf((float)(v.y + 1));
    if (base + 2 < n) dinv[base + 2] = rsqrtf((float)(v.z + 1));
    if (base + 3 < n) dinv[base + 3] = rsqrtf((float)(v.w + 1));

    int s = v.x + v.y + v.z + v.w;
    lds1[t] = s;
    __syncthreads();
    #pragma unroll
    for (int d = 1; d < 256; d <<= 1) {
        int u = (t >= d) ? lds1[t - d] : 0;
        __syncthreads();
        lds1[t] += u;
        __syncthreads();
    }
    int excl = lds1[t] - s;
    if (t == 255) bsum[blockIdx.x] = lds1[t];

    if (base + 3 < n) {
        int4 o;
        o.x = excl; o.y = excl + v.x; o.z = o.y + v.y; o.w = o.z + v.z;
        *reinterpret_cast<int4*>(offs + base) = o;
    } else {
        int e = excl;
        if (base + 0 < n) { offs[base + 0] = e; e += v.x; }
        if (base + 1 < n) { offs[base + 1] = e; e += v.y; }
        if (base + 2 < n) { offs[base + 2] = e; }
    }
}

__device__ void scan2_body(int* __restrict__ bsum, int nb) {
    __shared__ int lds2[256];
    int t = threadIdx.x;
    int v = (t < nb) ? bsum[t] : 0;
    lds2[t] = v;
    __syncthreads();
    #pragma unroll
    for (int d = 1; d < 256; d <<= 1) {
        int u = (t >= d) ? lds2[t - d] : 0;
        __syncthreads();
        lds2[t] += u;
        __syncthreads();
    }
    if (t < nb) bsum[t] = lds2[t] - v;  // exclusive
}

__device__ void scan3_body(int* __restrict__ offs, const int* __restrict__ bsum, int n) {
    int base = blockIdx.x * 1024 + threadIdx.x * 4;
    int add = bsum[blockIdx.x];
    if (base + 3 < n) {
        int4 o = *reinterpret_cast<int4*>(offs + base);
        o.x += add; o.y += add; o.z += add; o.w += add;
        *reinterpret_cast<int4*>(offs + base) = o;
    } else {
        for (int k = 0; k < 4; ++k)
            if (base + k < n) offs[base + k] += add;
    }
}

__device__ inline void bounds_body(const int* __restrict__ batch, int* __restrict__ start, int i, int n) {
    int b = batch[i];
    if (i == 0) {
        for (int g = 0; g <= b; ++g) start[g] = 0;
    } else {
        int pb = batch[i - 1];
        for (int g = pb + 1; g <= b; ++g) start[g] = i;
    }
    if (i == n - 1) {
        for (int g = b + 1; g <= NGRAPHS; ++g) start[g] = n;
    }
}

__device__ inline void cvt_body(const float* __restrict__ in, const float* __restrict__ dinv,
                                unsigned short* __restrict__ out, long long i) {
    int r = (int)(i >> 5);
    float d = dinv[r];
    float4 v = reinterpret_cast<const float4*>(in)[i];
    uint2 o;
    o.x = (unsigned)f2bf(v.x * d) | ((unsigned)f2bf(v.y * d) << 16);
    o.y = (unsigned)f2bf(v.z * d) | ((unsigned)f2bf(v.w * d) << 16);
    reinterpret_cast<uint2*>(out)[i] = o;
}

__device__ inline void wtrans_body(int idx, const float* __restrict__ W1, const float* __restrict__ W2,
                                   const float* __restrict__ W3, unsigned short* __restrict__ Wt1,
                                   unsigned short* __restrict__ Wt2, unsigned short* __restrict__ Wt3) {
    if (idx < 65536) {                      // W1: 128x512
        int k = idx >> 9, m = idx & 511;
        Wt1[m * 128 + k] = f2bf(W1[idx]);
    } else if (idx < 196608) {              // W2: 512x256
        int j = idx - 65536;
        int k = j >> 8, m = j & 255;
        Wt2[m * 512 + k] = f2bf(W2[j]);
    } else {                                // W3: 256x128
        int j = idx - 196608;
        int k = j >> 7, m = j & 127;
        Wt3[m * 256 + k] = f2bf(W3[j]);
    }
}

// CSR aggregation, grid-stride over groups of 4 nodes (1 wave per node)
template<int FC>
__device__ void agg_body(const unsigned short* __restrict__ in, const int* __restrict__ offs,
                         const int* __restrict__ cnt, const int* __restrict__ csr_row,
                         const float* __restrict__ dinv, unsigned short* __restrict__ out, int n) {
    constexpr int F   = 64 * FC;
    constexpr int LPE = (FC == 4) ? 32 : 16;   // lanes covering one row
    constexpr int EPL = 64 / LPE;              // edges per wave-iteration
    int wave = threadIdx.x >> 6;
    int lane = threadIdx.x & 63;
    int sub = lane / LPE;
    int fl  = lane % LPE;
    const size_t foff = (size_t)fl * 8;
    int ngrp = (n + 3) >> 2;

    for (int grp = blockIdx.x; grp < ngrp; grp += gridDim.x) {
        int node = grp * 4 + wave;
        if (node >= n) continue;

        float acc[8] = {};
        if (sub == 0) {  // self term, counted once
            uint4 u = *reinterpret_cast<const uint4*>(in + (size_t)node * F + foff);
            float v[8]; unpack8(u, v);
            #pragma unroll
            for (int i = 0; i < 8; ++i) acc[i] = v[i];
        }

        int s = offs[node], e1 = s + cnt[node];
        int eb = s;
        for (; eb + 2 * EPL <= e1; eb += 2 * EPL) {
            int r0 = csr_row[eb + sub];
            int r1 = csr_row[eb + EPL + sub];
            uint4 u0 = *reinterpret_cast<const uint4*>(in + (size_t)r0 * F + foff);
            uint4 u1 = *reinterpret_cast<const uint4*>(in + (size_t)r1 * F + foff);
            float v0[8], v1[8];
            unpack8(u0, v0); unpack8(u1, v1);
            #pragma unroll
            for (int i = 0; i < 8; ++i) acc[i] += v0[i] + v1[i];
        }
        for (; eb < e1; eb += EPL) {
            int e = eb + sub;
            bool ok = e < e1;
            int r = csr_row[ok ? e : e1 - 1];
            uint4 u = *reinterpret_cast<const uint4*>(in + (size_t)r * F + foff);
            float v[8]; unpack8(u, v);
            if (ok) {
                #pragma unroll
                for (int i = 0; i < 8; ++i) acc[i] += v[i];
            }
        }

        #pragma unroll
        for (int d = LPE; d < 64; d <<= 1) {
            #pragma unroll
            for (int i = 0; i < 8; ++i) acc[i] += __shfl_xor(acc[i], d, 64);
        }

        if (sub == 0) {
            float dn = dinv[node];
            uint4 o;
            o.x = (unsigned)f2bf(acc[0] * dn) | ((unsigned)f2bf(acc[1] * dn) << 16);
            o.y = (unsigned)f2bf(acc[2] * dn) | ((unsigned)f2bf(acc[3] * dn) << 16);
            o.z = (unsigned)f2bf(acc[4] * dn) | ((unsigned)f2bf(acc[5] * dn) << 16);
            o.w = (unsigned)f2bf(acc[6] * dn) | ((unsigned)f2bf(acc[7] * dn) << 16);
            *reinterpret_cast<uint4*>(out + (size_t)node * F + foff) = o;
        }
    }
}

// batchnorm stats, grid-stride
template<int F>
__device__ void bn_stats_body(const unsigned short* __restrict__ in, float* __restrict__ stat, int n) {
    constexpr int G   = F / 8;
    constexpr int RPP = 256 / G;
    int g  = threadIdx.x & (G - 1);
    int rl = threadIdx.x / G;

    float s[8] = {}, q[8] = {};
    for (int r = blockIdx.x * RPP + rl; r < n; r += gridDim.x * RPP) {
        uint4 u = *reinterpret_cast<const uint4*>(in + (size_t)r * F + g * 8);
        float v[8]; unpack8(u, v);
        #pragma unroll
        for (int i = 0; i < 8; ++i) { s[i] += v[i]; q[i] += v[i] * v[i]; }
    }

    __shared__ float ldsb[RPP][F];
    #pragma unroll
    for (int i = 0; i < 8; ++i) ldsb[rl][g * 8 + i] = s[i];
    __syncthreads();
    if (threadIdx.x < F) {
        float t = 0.f;
        #pragma unroll
        for (int rr = 0; rr < RPP; ++rr) t += ldsb[rr][threadIdx.x];
        atomicAdd(&stat[threadIdx.x], t);
    }
    __syncthreads();
    #pragma unroll
    for (int i = 0; i < 8; ++i) ldsb[rl][g * 8 + i] = q[i];
    __syncthreads();
    if (threadIdx.x < F) {
        float t = 0.f;
        #pragma unroll
        for (int rr = 0; rr < RPP; ++rr) t += ldsb[rr][threadIdx.x];
        atomicAdd(&stat[F + threadIdx.x], t);
    }
}

// pool with fused BN(stat3)+ReLU, grid-stride over 256 (g,q) jobs
__device__ void pool_body(const unsigned short* __restrict__ a, const int* __restrict__ start,
                          const float* __restrict__ stat3, const float* __restrict__ g3,
                          const float* __restrict__ be3, float invn, float* __restrict__ partial) {
    __shared__ float scp[128], shp[128];
    __shared__ float red[16][128];
    int tid = threadIdx.x;
    if (tid < 128) {
        float mean = stat3[tid] * invn;
        float var  = stat3[128 + tid] * invn - mean * mean;
        float sc = g3[tid] * rsqrtf(var + 1e-5f);
        scp[tid] = sc;
        shp[tid] = be3[tid] - mean * sc;
    }
    __syncthreads();
    int tf = tid & 15, tr = tid >> 4;
    float sc[8], sh[8];
    #pragma unroll
    for (int i = 0; i < 8; ++i) { sc[i] = scp[tf * 8 + i]; sh[i] = shp[tf * 8 + i]; }

    for (int job = blockIdx.x; job < NGRAPHS * 4; job += gridDim.x) {
        int g = job >> 2, q = job & 3;
        int s = start[g], e = start[g + 1];
        int nr = e - s;
        int c0 = s + (nr * q) / 4, c1 = s + (nr * (q + 1)) / 4;

        float acc[8] = {};
        for (int r = c0 + tr; r < c1; r += 16) {
            uint4 u = *reinterpret_cast<const uint4*>(a + (size_t)r * 128 + tf * 8);
            float v[8]; unpack8(u, v);
            #pragma unroll
            for (int i = 0; i < 8; ++i) acc[i] += fmaxf(v[i] * sc[i] + sh[i], 0.f);
        }
        #pragma unroll
        for (int i = 0; i < 8; ++i) red[tr][tf * 8 + i] = acc[i];
        __syncthreads();
        if (tid < 128) {
            float s2 = 0.f;
            #pragma unroll
            for (int t = 0; t < 16; ++t) s2 += red[t][tid];
            partial[((size_t)job) * 128 + tid] = s2;
        }
        __syncthreads();
    }
}

__device__ void final_body(const float* __restrict__ partial, const int* __restrict__ start,
                           const float* __restrict__ Wo, const float* __restrict__ bo,
                           float* __restrict__ out, int gtid, int gsz) {
    for (int idx = gtid; idx < NGRAPHS * 10; idx += gsz) {
        int g = idx / 10, c = idx - g * 10;
        float cntf = (float)(start[g + 1] - start[g]);
        float inv = 1.0f / fmaxf(cntf, 1.0f);
        float s = bo[c];
        for (int k = 0; k < 128; ++k) {
            float pk = partial[(size_t)(g * 4 + 0) * 128 + k] + partial[(size_t)(g * 4 + 1) * 128 + k]
                     + partial[(size_t)(g * 4 + 2) * 128 + k] + partial[(size_t)(g * 4 + 3) * 128 + k];
            s += pk * inv * Wo[k * 10 + c];
        }
        out[idx] = s;
    }
}

// ================= cooperative kernels =================

struct PrepArgs {
    const float* x; const int* row; const int* col; const int* bat;
    const float* W1; const float* W2; const float* W3;
    int* cnt; int* fill; float* statall; int* offs; int* bsum; float* dinv; int* start;
    int* csr_row;
    unsigned short* Wt1; unsigned short* Wt2; unsigned short* Wt3;
    unsigned short* xs; unsigned short* ax;
    int n; int ne; int nb;
};

__global__ __launch_bounds__(256) void prep_coop_k(PrepArgs a) {
    cg::grid_group grid = cg::this_grid();
    int gsz  = gridDim.x * 256;
    int gtid = blockIdx.x * 256 + threadIdx.x;

    // P0: zero cnt, fill, stats
    for (int i = gtid; i < a.n; i += gsz) { a.cnt[i] = 0; a.fill[i] = 0; }
    for (int i = gtid; i < 3 * 1024; i += gsz) a.statall[i] = 0.f;
    grid.sync();
    // P1: degree count
    for (int e = gtid; e < a.ne; e += gsz) atomicAdd(&a.cnt[a.col[e]], 1);
    grid.sync();
    // P2: 3-phase scan (+dinv)
    if (blockIdx.x < a.nb) scan1_body(a.cnt, a.offs, a.bsum, a.dinv, a.n);
    grid.sync();
    if (blockIdx.x == 0) scan2_body(a.bsum, a.nb);
    grid.sync();
    if (blockIdx.x < a.nb) scan3_body(a.offs, a.bsum, a.n);
    grid.sync();
    // P3: scatter + bounds + cvt + wtrans (mutually independent)
    for (int e = gtid; e < a.ne; e += gsz) {
        int r = a.row[e], c = a.col[e];
        int pos = a.offs[c] + atomicAdd(&a.fill[c], 1);
        a.csr_row[pos] = r;
    }
    for (int i = gtid; i < a.n; i += gsz) bounds_body(a.bat, a.start, i, a.n);
    long long total4 = (long long)a.n * 32;
    for (long long i = gtid; i < total4; i += gsz) cvt_body(a.x, a.dinv, a.xs, i);
    for (int i = gtid; i < 229376; i += gsz) wtrans_body(i, a.W1, a.W2, a.W3, a.Wt1, a.Wt2, a.Wt3);
    grid.sync();
    // P4: agg layer-1 input
    agg_body<2>(a.xs, a.offs, a.cnt, a.csr_row, a.dinv, a.ax, a.n);
}

struct MidArgs {
    const unsigned short* t2s; const int* offs; const int* cnt; const int* csr_row;
    const float* dinv; unsigned short* a2; float* stat2; int n;
};

__global__ __launch_bounds__(256) void mid_coop_k(MidArgs a) {
    cg::grid_group grid = cg::this_grid();
    agg_body<4>(a.t2s, a.offs, a.cnt, a.csr_row, a.dinv, a.a2, a.n);
    grid.sync();
    bn_stats_body<256>(a.a2, a.stat2, a.n);
}

struct TailArgs {
    const unsigned short* t3s; const int* offs; const int* cnt; const int* csr_row;
    const float* dinv; unsigned short* a3; float* stat3;
    const float* g3; const float* be3; const int* start;
    const float* Wo; const float* bo; float* partial; float* out; int n;
};

__global__ __launch_bounds__(256) void tail_coop_k(TailArgs a) {
    cg::grid_group grid = cg::this_grid();
    agg_body<2>(a.t3s, a.offs, a.cnt, a.csr_row, a.dinv, a.a3, a.n);
    grid.sync();
    bn_stats_body<128>(a.a3, a.stat3, a.n);
    grid.sync();
    pool_body(a.a3, a.start, a.stat3, a.g3, a.be3, 1.0f / a.n, a.partial);
    grid.sync();
    final_body(a.partial, a.start, a.Wo, a.bo, a.out, blockIdx.x * 256 + threadIdx.x, gridDim.x * 256);
}

// ================= GEMM (regular launch) =================
// BN_STAT: A'[r][k]=relu(A*sc[k]+sh[k]) with sc/sh computed from raw stats in LDS.
// SCALE_OUT: C row *= dinv[row].  STATS: column sum/sumsq -> atomics (raw stats out).
template<bool BN_STAT, bool SCALE_OUT, bool STATS>
__global__ __launch_bounds__(256) void gemm_bt_k(const unsigned short* __restrict__ A,
                                                 const unsigned short* __restrict__ B,
                                                 unsigned short* __restrict__ C,
                                                 const float* __restrict__ stat_in,
                                                 const float* __restrict__ gamma,
                                                 const float* __restrict__ beta,
                                                 float invn,
                                                 const float* __restrict__ dinv,
                                                 float* __restrict__ sums,
                                                 float* __restrict__ sqs,
                                                 int n, int K, int M) {
    __shared__ unsigned short As[128][40];
    __shared__ unsigned short Bs[128][40];
    __shared__ float scs[BN_STAT ? 512 : 1];
    __shared__ float shs[BN_STAT ? 512 : 1];
    int tid = threadIdx.x;

    if (BN_STAT) {
        for (int f = tid; f < K; f += 256) {
            float mean = stat_in[f] * invn;
            float var  = stat_in[K + f] * invn - mean * mean;
            float sc = gamma[f] * rsqrtf(var + 1e-5f);
            scs[f] = sc;
            shs[f] = beta[f] - mean * sc;
        }
        __syncthreads();
    }

    int wid = tid >> 6, lane = tid & 63;
    int wr = wid >> 1, wc = wid & 1;
    int row0 = blockIdx.y * 128, col0 = blockIdx.x * 128;

    f32x4 acc[4][4] = {};

    for (int kt = 0; kt < K; kt += 32) {
        int c8 = (tid & 3) * 8;
        float4 sc0, sc1, sh0, sh1;
        if (BN_STAT) {
            sc0 = *reinterpret_cast<const float4*>(&scs[kt + c8]);
            sc1 = *reinterpret_cast<const float4*>(&scs[kt + c8 + 4]);
            sh0 = *reinterpret_cast<const float4*>(&shs[kt + c8]);
            sh1 = *reinterpret_cast<const float4*>(&shs[kt + c8 + 4]);
        }
        #pragma unroll
        for (int h = 0; h < 2; ++h) {
            int r = (tid >> 2) + h * 64;
            int gr = row0 + r;
            bf16x8 va = {};
            if (gr < n) va = *reinterpret_cast<const bf16x8*>(A + (size_t)gr * K + kt + c8);
            if (BN_STAT) {
                #pragma unroll
                for (int t = 0; t < 8; ++t) {
                    float sct = (t < 4) ? (&sc0.x)[t] : (&sc1.x)[t - 4];
                    float sht = (t < 4) ? (&sh0.x)[t] : (&sh1.x)[t - 4];
                    float f = bf2f((unsigned short)va[t]);
                    va[t] = (short)f2bf(fmaxf(f * sct + sht, 0.f));
                }
            }
            *reinterpret_cast<bf16x8*>(&As[r][c8]) = va;
            bf16x8 vb = *reinterpret_cast<const bf16x8*>(B + (size_t)(col0 + r) * K + kt + c8);
            *reinterpret_cast<bf16x8*>(&Bs[r][c8]) = vb;
        }
        __syncthreads();

        bf16x8 af[4], bfr[4];
        int koff = (lane >> 4) * 8;
        #pragma unroll
        for (int f = 0; f < 4; ++f) {
            af[f]  = *reinterpret_cast<const bf16x8*>(&As[wr * 64 + f * 16 + (lane & 15)][koff]);
            bfr[f] = *reinterpret_cast<const bf16x8*>(&Bs[wc * 64 + f * 16 + (lane & 15)][koff]);
        }
        #pragma unroll
        for (int i = 0; i < 4; ++i)
            #pragma unroll
            for (int j = 0; j < 4; ++j)
                acc[i][j] = __builtin_amdgcn_mfma_f32_16x16x32_bf16(af[i], bfr[j], acc[i][j], 0, 0, 0);
        __syncthreads();
    }

    #pragma unroll
    for (int i = 0; i < 4; ++i) {
        #pragma unroll
        for (int q = 0; q < 4; ++q) {
            int gr = row0 + wr * 64 + i * 16 + (lane >> 4) * 4 + q;
            if (gr < n) {
                float dr = SCALE_OUT ? dinv[gr] : 1.0f;
                #pragma unroll
                for (int j = 0; j < 4; ++j) {
                    int gc = col0 + wc * 64 + j * 16 + (lane & 15);
                    C[(size_t)gr * M + gc] = f2bf(acc[i][j][q] * dr);
                }
            }
        }
    }

    if (STATS) {
        #pragma unroll
        for (int j = 0; j < 4; ++j) {
            float s = 0.f, q = 0.f;
            #pragma unroll
            for (int i = 0; i < 4; ++i)
                #pragma unroll
                for (int p = 0; p < 4; ++p) {
                    float v = acc[i][j][p];
                    s += v; q += v * v;
                }
            s += __shfl_xor(s, 16, 64); s += __shfl_xor(s, 32, 64);
            q += __shfl_xor(q, 16, 64); q += __shfl_xor(q, 32, 64);
            if ((lane >> 4) == 0) {
                int gc = col0 + wc * 64 + j * 16 + (lane & 15);
                atomicAdd(&sums[gc], s);
                atomicAdd(&sqs[gc], q);
            }
        }
    }
}

// ================= fallback (non-cooperative) wrappers =================

__global__ void deg_count_k(const int* __restrict__ col, int* __restrict__ cnt, int ne) {
    int i = blockIdx.x * blockDim.x + threadIdx.x;
    if (i < ne) atomicAdd(&cnt[col[i]], 1);
}
__global__ __launch_bounds__(256) void scan1_k(const int* cnt, int* offs, int* bsum, float* dinv, int n) {
    scan1_body(cnt, offs, bsum, dinv, n);
}
__global__ __launch_bounds__(256) void scan2_k(int* bsum, int nb) { scan2_body(bsum, nb); }
__global__ __launch_bounds__(256) void scan3_k(int* offs, const int* bsum, int n) { scan3_body(offs, bsum, n); }

// scatter + bounds + cvt + wtrans fused (all independent)
__global__ void prep3_k(const int* __restrict__ row_, const int* __restrict__ col_,
                        const int* __restrict__ offs, int* __restrict__ fill, int* __restrict__ csr_row,
                        const int* __restrict__ bat, int* __restrict__ start,
                        const float* __restrict__ x, const float* __restrict__ dinv,
                        unsigned short* __restrict__ xs,
                        const float* __restrict__ W1, const float* __restrict__ W2, const float* __restrict__ W3,
                        unsigned short* __restrict__ Wt1, unsigned short* __restrict__ Wt2,
                        unsigned short* __restrict__ Wt3, int n, int ne) {
    int gsz  = gridDim.x * blockDim.x;
    int gtid = blockIdx.x * blockDim.x + threadIdx.x;
    for (int e = gtid; e < ne; e += gsz) {
        int r = row_[e], c = col_[e];
        int pos = offs[c] + atomicAdd(&fill[c], 1);
        csr_row[pos] = r;
    }
    for (int i = gtid; i < n; i += gsz) bounds_body(bat, start, i, n);
    long long total4 = (long long)n * 32;
    for (long long i = gtid; i < total4; i += gsz) cvt_body(x, dinv, xs, i);
    for (int i = gtid; i < 229376; i += gsz) wtrans_body(i, W1, W2, W3, Wt1, Wt2, Wt3);
}

template<int FC>
__global__ void agg_k(const unsigned short* in, const int* offs, const int* cnt, const int* csr_row,
                      const float* dinv, unsigned short* out, int n) {
    agg_body<FC>(in, offs, cnt, csr_row, dinv, out, n);
}
template<int F>
__global__ __launch_bounds__(256) void bn_stats_k(const unsigned short* in, float* stat, int n) {
    bn_stats_body<F>(in, stat, n);
}
__global__ __launch_bounds__(256) void pool_k(const unsigned short* a, const int* start,
                                              const float* stat3, const float* g3, const float* be3,
                                              float invn, float* partial) {
    pool_body(a, start, stat3, g3, be3, invn, partial);
}
__global__ void final_out_k(const float* partial, const int* start, const float* Wo,
                            const float* bo, float* out) {
    final_body(partial, start, Wo, bo, out, blockIdx.x * blockDim.x + threadIdx.x,
               gridDim.x * blockDim.x);
}

// ================= driver =================

extern "C" void kernel_launch(void* const* d_in, const int* in_sizes, int n_in,
                              void* d_out, int out_size, void* d_ws, size_t ws_size,
                              hipStream_t stream) {
    const float* x   = (const float*)d_in[0];
    const int*   ei  = (const int*)d_in[1];
    const int*   bat = (const int*)d_in[2];
    const float* W1  = (const float*)d_in[3];
    const float* g1  = (const float*)d_in[5];
    const float* be1 = (const float*)d_in[6];
    const float* W2  = (const float*)d_in[7];
    const float* g2  = (const float*)d_in[9];
    const float* be2 = (const float*)d_in[10];
    const float* W3  = (const float*)d_in[11];
    const float* g3  = (const float*)d_in[13];
    const float* be3 = (const float*)d_in[14];
    const float* Wo  = (const float*)d_in[15];
    const float* bo  = (const float*)d_in[16];
    float* out = (float*)d_out;

    const int n  = in_sizes[2];       // 50000
    const int ne = in_sizes[1] / 2;   // 800000
    const int* row = ei;
    const int* col = ei + ne;
    const int NB = (n + 1023) / 1024;

    char* base = (char*)d_ws;
    size_t o = 0;
    auto alloc = [&](size_t bytes) -> char* {
        char* p = base + o;
        o += (bytes + 255) & ~(size_t)255;
        return p;
    };
    int*   cntfill = (int*)alloc((size_t)2 * n * 4);
    int*   cnt  = cntfill;
    int*   fill = cntfill + n;
    float* statall = (float*)alloc((size_t)3 * 1024 * 4);
    float* stat1 = statall;
    float* stat2 = statall + 1024;
    float* stat3 = statall + 2048;

    int*   offs  = (int*)alloc(n * 4);
    int*   bsum  = (int*)alloc(256 * 4);
    float* dinv  = (float*)alloc(n * 4);
    int*   start = (int*)alloc((NGRAPHS + 1) * 4);
    float* partial = (float*)alloc((size_t)NGRAPHS * 4 * 128 * 4);
    int*   csr_row = (int*)alloc((size_t)ne * 4);
    unsigned short* Wt1 = (unsigned short*)alloc((size_t)128 * 512 * 2);
    unsigned short* Wt2 = (unsigned short*)alloc((size_t)512 * 256 * 2);
    unsigned short* Wt3 = (unsigned short*)alloc((size_t)256 * 128 * 2);
    unsigned short* xs_bf  = (unsigned short*)alloc((size_t)n * 128 * 2);
    unsigned short* ax_bf  = (unsigned short*)alloc((size_t)n * 128 * 2);
    unsigned short* h1_bf  = (unsigned short*)alloc((size_t)n * 512 * 2);
    unsigned short* t2s_bf = (unsigned short*)alloc((size_t)n * 256 * 2);
    unsigned short* a2_bf  = (unsigned short*)alloc((size_t)n * 256 * 2);
    unsigned short* t3s_bf = (unsigned short*)alloc((size_t)n * 128 * 2);
    unsigned short* a3_bf  = (unsigned short*)alloc((size_t)n * 128 * 2);

    const float invn = 1.0f / (float)n;

    PrepArgs pa = { x, row, col, bat, W1, W2, W3, cnt, fill, statall, offs, bsum, dinv, start,
                    csr_row, Wt1, Wt2, Wt3, xs_bf, ax_bf, n, ne, NB };
    MidArgs  ma = { t2s_bf, offs, cnt, csr_row, dinv, a2_bf, stat2, n };
    TailArgs ta = { t3s_bf, offs, cnt, csr_row, dinv, a3_bf, stat3, g3, be3, start,
                    Wo, bo, partial, out, n };

    // ---- prep (cooperative, with per-kernel fallback) ----
    bool coop = true;
    {
        int occ = 0;
        if (hipOccupancyMaxActiveBlocksPerMultiprocessor(&occ, prep_coop_k, 256, 0) != hipSuccess || occ < 1)
            occ = 2;
        int G = occ * 256; if (G > 4096) G = 4096;
        void* args[] = { &pa };
        hipError_t e = hipLaunchCooperativeKernel((const void*)prep_coop_k, dim3(G), dim3(256), args, 0, stream);
        if (e != hipSuccess) { coop = false; (void)hipGetLastError(); }
    }
    if (!coop) {
        hipMemsetAsync(cntfill, 0, (size_t)2 * n * 4, stream);
        hipMemsetAsync(statall, 0, 3 * 1024 * 4, stream);
        deg_count_k<<<(ne + 255) / 256, 256, 0, stream>>>(col, cnt, ne);
        scan1_k<<<NB, 256, 0, stream>>>(cnt, offs, bsum, dinv, n);
        scan2_k<<<1, 256, 0, stream>>>(bsum, NB);
        scan3_k<<<NB, 256, 0, stream>>>(offs, bsum, n);
        prep3_k<<<2048, 256, 0, stream>>>(row, col, offs, fill, csr_row, bat, start,
                                          x, dinv, xs_bf, W1, W2, W3, Wt1, Wt2, Wt3, n, ne);
        agg_k<2><<<(n + 3) / 4, 256, 0, stream>>>(xs_bf, offs, cnt, csr_row, dinv, ax_bf, n);
    }

    // ---- GEMM 1: ax @ W1 -> h1, fused raw column stats -> stat1 ----
    gemm_bt_k<false, false, true><<<dim3(4, (n + 127) / 128), 256, 0, stream>>>(
        ax_bf, Wt1, h1_bf, nullptr, nullptr, nullptr, 0.f, nullptr, stat1, stat1 + 512, n, 128, 512);

    // ---- GEMM 2: bn+relu(h1; stat1) @ W2 -> t2s (row-prescaled by dinv) ----
    gemm_bt_k<true, true, false><<<dim3(2, (n + 127) / 128), 256, 0, stream>>>(
        h1_bf, Wt2, t2s_bf, stat1, g1, be1, invn, dinv, nullptr, nullptr, n, 512, 256);

    // ---- mid: agg<4> + bn_stats<256> ----
    if (coop) {
        int occ = 0;
        if (hipOccupancyMaxActiveBlocksPerMultiprocessor(&occ, mid_coop_k, 256, 0) != hipSuccess || occ < 1)
            occ = 2;
        int G = occ * 256; if (G > 4096) G = 4096;
        void* args[] = { &ma };
        hipError_t e = hipLaunchCooperativeKernel((const void*)mid_coop_k, dim3(G), dim3(256), args, 0, stream);
        if (e != hipSuccess) { coop = false; (void)hipGetLastError(); }
    }
    if (!coop) {
        agg_k<4><<<(n + 3) / 4, 256, 0, stream>>>(t2s_bf, offs, cnt, csr_row, dinv, a2_bf, n);
        bn_stats_k<256><<<1024, 256, 0, stream>>>(a2_bf, stat2, n);
    }

    // ---- GEMM 3: bn+relu(a2; stat2) @ W3 -> t3s (row-prescaled) ----
    gemm_bt_k<true, true, false><<<dim3(1, (n + 127) / 128), 256, 0, stream>>>(
        a2_bf, Wt3, t3s_bf, stat2, g2, be2, invn, dinv, nullptr, nullptr, n, 256, 128);

    // ---- tail: agg<2> + bn_stats<128> + pool + final ----
    if (coop) {
        int occ = 0;
        if (hipOccupancyMaxActiveBlocksPerMultiprocessor(&occ, tail_coop_k, 256, 0) != hipSuccess || occ < 1)
            occ = 2;
        int G = occ * 256; if (G > 4096) G = 4096;
        void* args[] = { &ta };
        hipError_t e = hipLaunchCooperativeKernel((const void*)tail_coop_k, dim3(G), dim3(256), args, 0, stream);
        if (e != hipSuccess) { coop = false; (void)hipGetLastError(); }
    }
    if (!coop) {
        agg_k<2><<<(n + 3) / 4, 256, 0, stream>>>(t3s_bf, offs, cnt, csr_row, dinv, a3_bf, n);
        bn_stats_k<128><<<1024, 256, 0, stream>>>(a3_bf, stat3, n);
        pool_k<<<256, 256, 0, stream>>>(a3_bf, start, stat3, g3, be3, invn, partial);
        final_out_k<<<3, 256, 0, stream>>>(partial, start, Wo, bo, out);
    }
}

// Round 13
// 491.011 us; speedup vs baseline: 4.0804x; 4.0804x over previous
//
#include <hip/hip_runtime.h>
#include <hip/hip_bf16.h>
#include <cstdint>
#include <cstddef>

#define NGRAPHS 64

typedef short bf16x8 __attribute__((ext_vector_type(8)));
typedef float f32x4 __attribute__((ext_vector_type(4)));

__device__ inline float bf2f(unsigned short u) {
    return __uint_as_float(((unsigned)u) << 16);
}
__device__ inline unsigned short f2bf(float f) {
    unsigned u = __float_as_uint(f);
    return (unsigned short)((u + 0x7fff + ((u >> 16) & 1)) >> 16);  // RNE
}
__device__ inline void unpack8(uint4 u, float* v) {
    v[0] = bf2f((unsigned short)(u.x & 0xffff)); v[1] = bf2f((unsigned short)(u.x >> 16));
    v[2] = bf2f((unsigned short)(u.y & 0xffff)); v[3] = bf2f((unsigned short)(u.y >> 16));
    v[4] = bf2f((unsigned short)(u.z & 0xffff)); v[5] = bf2f((unsigned short)(u.z >> 16));
    v[6] = bf2f((unsigned short)(u.w & 0xffff)); v[7] = bf2f((unsigned short)(u.w >> 16));
}

// ---------------- degree ----------------
__global__ void deg_count_k(const int* __restrict__ col, int* __restrict__ cnt, int ne) {
    int i = blockIdx.x * blockDim.x + threadIdx.x;
    if (i < ne) atomicAdd(&cnt[col[i]], 1);
}

// ---------------- multi-block exclusive scan (1024 elems/block) + dinv ----------------
__global__ __launch_bounds__(256) void scan1_k(const int* __restrict__ cnt, int* __restrict__ offs,
                                               int* __restrict__ bsum, float* __restrict__ dinv, int n) {
    int t = threadIdx.x;
    int base = blockIdx.x * 1024 + t * 4;
    int4 v = {0, 0, 0, 0};
    if (base + 3 < n) v = *reinterpret_cast<const int4*>(cnt + base);
    else {
        if (base + 0 < n) v.x = cnt[base + 0];
        if (base + 1 < n) v.y = cnt[base + 1];
        if (base + 2 < n) v.z = cnt[base + 2];
    }
    if (base + 0 < n) dinv[base + 0] = rsqrtf((float)(v.x + 1));
    if (base + 1 < n) dinv[base + 1] = rsqrtf((float)(v.y + 1));
    if (base + 2 < n) dinv[base + 2] = rsqrtf((float)(v.z + 1));
    if (base + 3 < n) dinv[base + 3] = rsqrtf((float)(v.w + 1));

    int s = v.x + v.y + v.z + v.w;
    __shared__ int lds[256];
    lds[t] = s;
    __syncthreads();
    #pragma unroll
    for (int d = 1; d < 256; d <<= 1) {
        int u = (t >= d) ? lds[t - d] : 0;
        __syncthreads();
        lds[t] += u;
        __syncthreads();
    }
    int excl = lds[t] - s;
    if (t == 255) bsum[blockIdx.x] = lds[t];

    if (base + 3 < n) {
        int4 o;
        o.x = excl; o.y = excl + v.x; o.z = o.y + v.y; o.w = o.z + v.z;
        *reinterpret_cast<int4*>(offs + base) = o;
    } else {
        int e = excl;
        if (base + 0 < n) { offs[base + 0] = e; e += v.x; }
        if (base + 1 < n) { offs[base + 1] = e; e += v.y; }
        if (base + 2 < n) { offs[base + 2] = e; }
    }
}

__global__ __launch_bounds__(256) void scan2_k(int* __restrict__ bsum, int nb) {
    __shared__ int lds[256];
    int t = threadIdx.x;
    int v = (t < nb) ? bsum[t] : 0;
    lds[t] = v;
    __syncthreads();
    #pragma unroll
    for (int d = 1; d < 256; d <<= 1) {
        int u = (t >= d) ? lds[t - d] : 0;
        __syncthreads();
        lds[t] += u;
        __syncthreads();
    }
    if (t < nb) bsum[t] = lds[t] - v;  // exclusive
}

__global__ __launch_bounds__(256) void scan3_k(int* __restrict__ offs, const int* __restrict__ bsum, int n) {
    int base = blockIdx.x * 1024 + threadIdx.x * 4;
    int add = bsum[blockIdx.x];
    if (base + 3 < n) {
        int4 o = *reinterpret_cast<int4*>(offs + base);
        o.x += add; o.y += add; o.z += add; o.w += add;
        *reinterpret_cast<int4*>(offs + base) = o;
    } else {
        for (int k = 0; k < 4; ++k)
            if (base + k < n) offs[base + k] += add;
    }
}

// ---------------- fused: scatter + bounds + cvt + wtrans (grid-stride, independent jobs) ----------------
__global__ void prep3_k(const int* __restrict__ row_, const int* __restrict__ col_,
                        const int* __restrict__ offs, int* __restrict__ fill, int* __restrict__ csr_row,
                        const int* __restrict__ bat, int* __restrict__ start,
                        const float* __restrict__ x, const float* __restrict__ dinv,
                        unsigned short* __restrict__ xs,
                        const float* __restrict__ W1, const float* __restrict__ W2, const float* __restrict__ W3,
                        unsigned short* __restrict__ Wt1, unsigned short* __restrict__ Wt2,
                        unsigned short* __restrict__ Wt3, int n, int ne) {
    int gsz  = gridDim.x * blockDim.x;
    int gtid = blockIdx.x * blockDim.x + threadIdx.x;
    // CSR scatter
    for (int e = gtid; e < ne; e += gsz) {
        int r = row_[e], c = col_[e];
        int pos = offs[c] + atomicAdd(&fill[c], 1);
        csr_row[pos] = r;
    }
    // graph bounds
    for (int i = gtid; i < n; i += gsz) {
        int b = bat[i];
        if (i == 0) {
            for (int g = 0; g <= b; ++g) start[g] = 0;
        } else {
            int pb = bat[i - 1];
            for (int g = pb + 1; g <= b; ++g) start[g] = i;
        }
        if (i == n - 1) {
            for (int g = b + 1; g <= NGRAPHS; ++g) start[g] = n;
        }
    }
    // x -> bf16 with dinv prescale
    long long total4 = (long long)n * 32;
    for (long long i = gtid; i < total4; i += gsz) {
        int r = (int)(i >> 5);
        float d = dinv[r];
        float4 v = reinterpret_cast<const float4*>(x)[i];
        uint2 o;
        o.x = (unsigned)f2bf(v.x * d) | ((unsigned)f2bf(v.y * d) << 16);
        o.y = (unsigned)f2bf(v.z * d) | ((unsigned)f2bf(v.w * d) << 16);
        reinterpret_cast<uint2*>(xs)[i] = o;
    }
    // weight transpose + convert
    for (int idx = gtid; idx < 229376; idx += gsz) {
        if (idx < 65536) {                      // W1: 128x512
            int k = idx >> 9, m = idx & 511;
            Wt1[m * 128 + k] = f2bf(W1[idx]);
        } else if (idx < 196608) {              // W2: 512x256
            int j = idx - 65536;
            int k = j >> 8, m = j & 255;
            Wt2[m * 512 + k] = f2bf(W2[j]);
        } else {                                // W3: 256x128
            int j = idx - 196608;
            int k = j >> 7, m = j & 127;
            Wt3[m * 256 + k] = f2bf(W3[j]);
        }
    }
}

// ---------------- CSR aggregation: multi-edge waves, uint4 (16B) lanes ----------------
// out[c] = f2bf( dinv[c] * ( in[c] + sum_{e in CSR[c]} in[row[e]] ) )   (input prescaled by dinv[r])
template<int FC>
__global__ void agg_s_k(const unsigned short* __restrict__ in, const int* __restrict__ offs,
                        const int* __restrict__ cnt, const int* __restrict__ csr_row,
                        const float* __restrict__ dinv, unsigned short* __restrict__ out, int n) {
    constexpr int F   = 64 * FC;
    constexpr int LPE = (FC == 4) ? 32 : 16;   // lanes covering one row
    constexpr int EPL = 64 / LPE;              // edges per wave-iteration
    int node = blockIdx.x * 4 + (threadIdx.x >> 6);
    if (node >= n) return;
    int lane = threadIdx.x & 63;
    int sub = lane / LPE;
    int fl  = lane % LPE;
    const size_t foff = (size_t)fl * 8;

    float acc[8] = {};
    if (sub == 0) {  // self term, counted once
        uint4 u = *reinterpret_cast<const uint4*>(in + (size_t)node * F + foff);
        float v[8]; unpack8(u, v);
        #pragma unroll
        for (int i = 0; i < 8; ++i) acc[i] = v[i];
    }

    int s = offs[node], e1 = s + cnt[node];
    int eb = s;
    for (; eb + 2 * EPL <= e1; eb += 2 * EPL) {
        int r0 = csr_row[eb + sub];
        int r1 = csr_row[eb + EPL + sub];
        uint4 u0 = *reinterpret_cast<const uint4*>(in + (size_t)r0 * F + foff);
        uint4 u1 = *reinterpret_cast<const uint4*>(in + (size_t)r1 * F + foff);
        float v0[8], v1[8];
        unpack8(u0, v0); unpack8(u1, v1);
        #pragma unroll
        for (int i = 0; i < 8; ++i) acc[i] += v0[i] + v1[i];
    }
    for (; eb < e1; eb += EPL) {
        int e = eb + sub;
        bool ok = e < e1;
        int r = csr_row[ok ? e : e1 - 1];
        uint4 u = *reinterpret_cast<const uint4*>(in + (size_t)r * F + foff);
        float v[8]; unpack8(u, v);
        if (ok) {
            #pragma unroll
            for (int i = 0; i < 8; ++i) acc[i] += v[i];
        }
    }

    #pragma unroll
    for (int d = LPE; d < 64; d <<= 1) {
        #pragma unroll
        for (int i = 0; i < 8; ++i) acc[i] += __shfl_xor(acc[i], d, 64);
    }

    if (sub == 0) {
        float dn = dinv[node];
        uint4 o;
        o.x = (unsigned)f2bf(acc[0] * dn) | ((unsigned)f2bf(acc[1] * dn) << 16);
        o.y = (unsigned)f2bf(acc[2] * dn) | ((unsigned)f2bf(acc[3] * dn) << 16);
        o.z = (unsigned)f2bf(acc[4] * dn) | ((unsigned)f2bf(acc[5] * dn) << 16);
        o.w = (unsigned)f2bf(acc[6] * dn) | ((unsigned)f2bf(acc[7] * dn) << 16);
        *reinterpret_cast<uint4*>(out + (size_t)node * F + foff) = o;
    }
}

// ---------------- bf16 MFMA GEMM ----------------
// BN_STAT: A'[r][k]=relu(A*sc[k]+sh[k]) with sc/sh computed from raw stats into LDS.
// SCALE_OUT: C row *= dinv[row].  STATS: column raw sum/sumsq -> atomics.
template<bool BN_STAT, bool SCALE_OUT, bool STATS>
__global__ __launch_bounds__(256) void gemm_bt_k(const unsigned short* __restrict__ A,
                                                 const unsigned short* __restrict__ B,
                                                 unsigned short* __restrict__ C,
                                                 const float* __restrict__ stat_in,
                                                 const float* __restrict__ gamma,
                                                 const float* __restrict__ beta,
                                                 float invn,
                                                 const float* __restrict__ dinv,
                                                 float* __restrict__ sums,
                                                 float* __restrict__ sqs,
                                                 int n, int K, int M) {
    __shared__ unsigned short As[128][40];
    __shared__ unsigned short Bs[128][40];
    __shared__ float scs[BN_STAT ? 512 : 1];
    __shared__ float shs[BN_STAT ? 512 : 1];
    int tid = threadIdx.x;

    if (BN_STAT) {
        for (int f = tid; f < K; f += 256) {
            float mean = stat_in[f] * invn;
            float var  = stat_in[K + f] * invn - mean * mean;
            float sc = gamma[f] * rsqrtf(var + 1e-5f);
            scs[f] = sc;
            shs[f] = beta[f] - mean * sc;
        }
        __syncthreads();
    }

    int wid = tid >> 6, lane = tid & 63;
    int wr = wid >> 1, wc = wid & 1;
    int row0 = blockIdx.y * 128, col0 = blockIdx.x * 128;

    f32x4 acc[4][4] = {};

    for (int kt = 0; kt < K; kt += 32) {
        int c8 = (tid & 3) * 8;
        float4 sc0, sc1, sh0, sh1;
        if (BN_STAT) {
            sc0 = *reinterpret_cast<const float4*>(&scs[kt + c8]);
            sc1 = *reinterpret_cast<const float4*>(&scs[kt + c8 + 4]);
            sh0 = *reinterpret_cast<const float4*>(&shs[kt + c8]);
            sh1 = *reinterpret_cast<const float4*>(&shs[kt + c8 + 4]);
        }
        #pragma unroll
        for (int h = 0; h < 2; ++h) {
            int r = (tid >> 2) + h * 64;
            int gr = row0 + r;
            bf16x8 va = {};
            if (gr < n) va = *reinterpret_cast<const bf16x8*>(A + (size_t)gr * K + kt + c8);
            if (BN_STAT) {
                #pragma unroll
                for (int t = 0; t < 8; ++t) {
                    float sct = (t < 4) ? (&sc0.x)[t] : (&sc1.x)[t - 4];
                    float sht = (t < 4) ? (&sh0.x)[t] : (&sh1.x)[t - 4];
                    float f = bf2f((unsigned short)va[t]);
                    va[t] = (short)f2bf(fmaxf(f * sct + sht, 0.f));
                }
            }
            *reinterpret_cast<bf16x8*>(&As[r][c8]) = va;
            bf16x8 vb = *reinterpret_cast<const bf16x8*>(B + (size_t)(col0 + r) * K + kt + c8);
            *reinterpret_cast<bf16x8*>(&Bs[r][c8]) = vb;
        }
        __syncthreads();

        bf16x8 af[4], bfr[4];
        int koff = (lane >> 4) * 8;
        #pragma unroll
        for (int f = 0; f < 4; ++f) {
            af[f]  = *reinterpret_cast<const bf16x8*>(&As[wr * 64 + f * 16 + (lane & 15)][koff]);
            bfr[f] = *reinterpret_cast<const bf16x8*>(&Bs[wc * 64 + f * 16 + (lane & 15)][koff]);
        }
        #pragma unroll
        for (int i = 0; i < 4; ++i)
            #pragma unroll
            for (int j = 0; j < 4; ++j)
                acc[i][j] = __builtin_amdgcn_mfma_f32_16x16x32_bf16(af[i], bfr[j], acc[i][j], 0, 0, 0);
        __syncthreads();
    }

    #pragma unroll
    for (int i = 0; i < 4; ++i) {
        #pragma unroll
        for (int q = 0; q < 4; ++q) {
            int gr = row0 + wr * 64 + i * 16 + (lane >> 4) * 4 + q;
            if (gr < n) {
                float dr = SCALE_OUT ? dinv[gr] : 1.0f;
                #pragma unroll
                for (int j = 0; j < 4; ++j) {
                    int gc = col0 + wc * 64 + j * 16 + (lane & 15);
                    C[(size_t)gr * M + gc] = f2bf(acc[i][j][q] * dr);
                }
            }
        }
    }

    if (STATS) {
        #pragma unroll
        for (int j = 0; j < 4; ++j) {
            float s = 0.f, q = 0.f;
            #pragma unroll
            for (int i = 0; i < 4; ++i)
                #pragma unroll
                for (int p = 0; p < 4; ++p) {
                    float v = acc[i][j][p];
                    s += v; q += v * v;
                }
            s += __shfl_xor(s, 16, 64); s += __shfl_xor(s, 32, 64);
            q += __shfl_xor(q, 16, 64); q += __shfl_xor(q, 32, 64);
            if ((lane >> 4) == 0) {
                int gc = col0 + wc * 64 + j * 16 + (lane & 15);
                atomicAdd(&sums[gc], s);
                atomicAdd(&sqs[gc], q);
            }
        }
    }
}

// ---------------- batchnorm stats: uint4 loads, LDS block-reduce, 2F atomics/block ----------------
template<int F>
__global__ __launch_bounds__(256) void bn_stats_k(const unsigned short* __restrict__ in,
                                                  float* __restrict__ stat, int n) {
    constexpr int G   = F / 8;
    constexpr int RPP = 256 / G;
    int g  = threadIdx.x & (G - 1);
    int rl = threadIdx.x / G;

    float s[8] = {}, q[8] = {};
    for (int r = blockIdx.x * RPP + rl; r < n; r += gridDim.x * RPP) {
        uint4 u = *reinterpret_cast<const uint4*>(in + (size_t)r * F + g * 8);
        float v[8]; unpack8(u, v);
        #pragma unroll
        for (int i = 0; i < 8; ++i) { s[i] += v[i]; q[i] += v[i] * v[i]; }
    }

    __shared__ float lds[RPP][F];
    #pragma unroll
    for (int i = 0; i < 8; ++i) lds[rl][g * 8 + i] = s[i];
    __syncthreads();
    if (threadIdx.x < F) {
        float t = 0.f;
        #pragma unroll
        for (int rr = 0; rr < RPP; ++rr) t += lds[rr][threadIdx.x];
        atomicAdd(&stat[threadIdx.x], t);
    }
    __syncthreads();
    #pragma unroll
    for (int i = 0; i < 8; ++i) lds[rl][g * 8 + i] = q[i];
    __syncthreads();
    if (threadIdx.x < F) {
        float t = 0.f;
        #pragma unroll
        for (int rr = 0; rr < RPP; ++rr) t += lds[rr][threadIdx.x];
        atomicAdd(&stat[F + threadIdx.x], t);
    }
}

// ---------------- pooling (fused BN finalize from raw stat3) ----------------
__global__ __launch_bounds__(256) void pool_part_k(const unsigned short* __restrict__ a,
                                                   const int* __restrict__ start,
                                                   const float* __restrict__ stat3,
                                                   const float* __restrict__ g3,
                                                   const float* __restrict__ be3,
                                                   float invn,
                                                   float* __restrict__ partial) {
    __shared__ float scp[128], shp[128];
    __shared__ float red[16][128];
    int tid = threadIdx.x;
    if (tid < 128) {
        float mean = stat3[tid] * invn;
        float var  = stat3[128 + tid] * invn - mean * mean;
        float sc = g3[tid] * rsqrtf(var + 1e-5f);
        scp[tid] = sc;
        shp[tid] = be3[tid] - mean * sc;
    }
    __syncthreads();

    int g = blockIdx.x, q = blockIdx.y;
    int s = start[g], e = start[g + 1];
    int nr = e - s;
    int c0 = s + (nr * q) / 4, c1 = s + (nr * (q + 1)) / 4;
    int tf = tid & 15, tr = tid >> 4;

    float sc[8], sh[8];
    #pragma unroll
    for (int i = 0; i < 8; ++i) { sc[i] = scp[tf * 8 + i]; sh[i] = shp[tf * 8 + i]; }

    float acc[8] = {};
    for (int r = c0 + tr; r < c1; r += 16) {
        uint4 u = *reinterpret_cast<const uint4*>(a + (size_t)r * 128 + tf * 8);
        float v[8]; unpack8(u, v);
        #pragma unroll
        for (int i = 0; i < 8; ++i) acc[i] += fmaxf(v[i] * sc[i] + sh[i], 0.f);
    }

    #pragma unroll
    for (int i = 0; i < 8; ++i) red[tr][tf * 8 + i] = acc[i];
    __syncthreads();
    if (tid < 128) {
        float s2 = 0.f;
        #pragma unroll
        for (int t = 0; t < 16; ++t) s2 += red[t][tid];
        partial[((size_t)(g * 4 + q)) * 128 + tid] = s2;
    }
}

__global__ void final_out_k(const float* __restrict__ partial, const int* __restrict__ start,
                            const float* __restrict__ Wo, const float* __restrict__ bo,
                            float* __restrict__ out) {
    int idx = blockIdx.x * blockDim.x + threadIdx.x;
    if (idx >= NGRAPHS * 10) return;
    int g = idx / 10, c = idx - g * 10;
    float cntf = (float)(start[g + 1] - start[g]);
    float inv = 1.0f / fmaxf(cntf, 1.0f);
    float s = bo[c];
    for (int k = 0; k < 128; ++k) {
        float pk = partial[(size_t)(g * 4 + 0) * 128 + k] + partial[(size_t)(g * 4 + 1) * 128 + k]
                 + partial[(size_t)(g * 4 + 2) * 128 + k] + partial[(size_t)(g * 4 + 3) * 128 + k];
        s += pk * inv * Wo[k * 10 + c];
    }
    out[idx] = s;
}

// ---------------- driver ----------------
extern "C" void kernel_launch(void* const* d_in, const int* in_sizes, int n_in,
                              void* d_out, int out_size, void* d_ws, size_t ws_size,
                              hipStream_t stream) {
    const float* x   = (const float*)d_in[0];
    const int*   ei  = (const int*)d_in[1];
    const int*   bat = (const int*)d_in[2];
    const float* W1  = (const float*)d_in[3];
    const float* g1  = (const float*)d_in[5];
    const float* be1 = (const float*)d_in[6];
    const float* W2  = (const float*)d_in[7];
    const float* g2  = (const float*)d_in[9];
    const float* be2 = (const float*)d_in[10];
    const float* W3  = (const float*)d_in[11];
    const float* g3  = (const float*)d_in[13];
    const float* be3 = (const float*)d_in[14];
    const float* Wo  = (const float*)d_in[15];
    const float* bo  = (const float*)d_in[16];
    float* out = (float*)d_out;

    const int n  = in_sizes[2];       // 50000
    const int ne = in_sizes[1] / 2;   // 800000
    const int* row = ei;
    const int* col = ei + ne;
    const int NB = (n + 1023) / 1024;

    char* base = (char*)d_ws;
    size_t o = 0;
    auto alloc = [&](size_t bytes) -> char* {
        char* p = base + o;
        o += (bytes + 255) & ~(size_t)255;
        return p;
    };
    // zero-init region: cnt | fill | stat1 | stat2 | stat3 (single memset, contiguous)
    int*   cntfill = (int*)alloc((size_t)2 * n * 4);
    int*   cnt  = cntfill;
    int*   fill = cntfill + n;
    float* statall = (float*)alloc((size_t)3 * 1024 * 4);
    float* stat1 = statall;            // 512 sums | 512 sqs
    float* stat2 = statall + 1024;     // 256 sums | 256 sqs
    float* stat3 = statall + 2048;     // 128 sums | 128 sqs
    size_t zspan = (size_t)((char*)(statall + 3 * 1024) - (char*)cntfill);

    int*   offs  = (int*)alloc(n * 4);
    int*   bsum  = (int*)alloc(256 * 4);
    float* dinv  = (float*)alloc(n * 4);
    int*   start = (int*)alloc((NGRAPHS + 1) * 4);
    float* partial = (float*)alloc((size_t)NGRAPHS * 4 * 128 * 4);
    int*   csr_row = (int*)alloc((size_t)ne * 4);
    unsigned short* Wt1 = (unsigned short*)alloc((size_t)128 * 512 * 2);
    unsigned short* Wt2 = (unsigned short*)alloc((size_t)512 * 256 * 2);
    unsigned short* Wt3 = (unsigned short*)alloc((size_t)256 * 128 * 2);
    unsigned short* xs_bf  = (unsigned short*)alloc((size_t)n * 128 * 2);
    unsigned short* ax_bf  = (unsigned short*)alloc((size_t)n * 128 * 2);
    unsigned short* h1_bf  = (unsigned short*)alloc((size_t)n * 512 * 2);
    unsigned short* t2s_bf = (unsigned short*)alloc((size_t)n * 256 * 2);
    unsigned short* a2_bf  = (unsigned short*)alloc((size_t)n * 256 * 2);
    unsigned short* t3s_bf = (unsigned short*)alloc((size_t)n * 128 * 2);
    unsigned short* a3_bf  = (unsigned short*)alloc((size_t)n * 128 * 2);

    const float invn = 1.0f / (float)n;

    // ---- graph preprocessing (regular launches; coop grid.sync is 100x worse on 8-XCD) ----
    hipMemsetAsync(cntfill, 0, zspan, stream);
    deg_count_k<<<(ne + 255) / 256, 256, 0, stream>>>(col, cnt, ne);
    scan1_k<<<NB, 256, 0, stream>>>(cnt, offs, bsum, dinv, n);
    scan2_k<<<1, 256, 0, stream>>>(bsum, NB);
    scan3_k<<<NB, 256, 0, stream>>>(offs, bsum, n);
    prep3_k<<<2048, 256, 0, stream>>>(row, col, offs, fill, csr_row, bat, start,
                                      x, dinv, xs_bf, W1, W2, W3, Wt1, Wt2, Wt3, n, ne);

    // ---- Layer 1: agg(xs)[128] -> @W1 [512] (+fused raw column stats) ----
    agg_s_k<2><<<(n + 3) / 4, 256, 0, stream>>>(xs_bf, offs, cnt, csr_row, dinv, ax_bf, n);
    gemm_bt_k<false, false, true><<<dim3(4, (n + 127) / 128), 256, 0, stream>>>(
        ax_bf, Wt1, h1_bf, nullptr, nullptr, nullptr, 0.f, nullptr, stat1, stat1 + 512, n, 128, 512);

    // ---- Layer 2: bn+relu(h1; stat1) @ W2 [256] (row-prescaled) -> agg -> stats ----
    gemm_bt_k<true, true, false><<<dim3(2, (n + 127) / 128), 256, 0, stream>>>(
        h1_bf, Wt2, t2s_bf, stat1, g1, be1, invn, dinv, nullptr, nullptr, n, 512, 256);
    agg_s_k<4><<<(n + 3) / 4, 256, 0, stream>>>(t2s_bf, offs, cnt, csr_row, dinv, a2_bf, n);
    bn_stats_k<256><<<1024, 256, 0, stream>>>(a2_bf, stat2, n);

    // ---- Layer 3: bn+relu(a2; stat2) @ W3 [128] (row-prescaled) -> agg -> stats ----
    gemm_bt_k<true, true, false><<<dim3(1, (n + 127) / 128), 256, 0, stream>>>(
        a2_bf, Wt3, t3s_bf, stat2, g2, be2, invn, dinv, nullptr, nullptr, n, 256, 128);
    agg_s_k<2><<<(n + 3) / 4, 256, 0, stream>>>(t3s_bf, offs, cnt, csr_row, dinv, a3_bf, n);
    bn_stats_k<128><<<1024, 256, 0, stream>>>(a3_bf, stat3, n);

    // ---- pool (fused BN finalize + ReLU) + output ----
    pool_part_k<<<dim3(NGRAPHS, 4), 256, 0, stream>>>(a3_bf, start, stat3, g3, be3, invn, partial);
    final_out_k<<<3, 256, 0, stream>>>(partial, start, Wo, bo, out);
}